// Round 20
// baseline (1278.769 us; speedup 1.0000x reference)
//
#include <hip/hip_runtime.h>
#include <hip/hip_bf16.h>

#define D 512
#define BATCH 2048
#define SEQ 32
#define MIND 16

typedef __hip_bfloat16 bf16;
typedef __attribute__((ext_vector_type(8))) short s8v;   // 8 bf16 = 16B (MFMA A/B frag)
typedef __attribute__((ext_vector_type(4))) short s4v;
typedef __attribute__((ext_vector_type(4))) float f4v;   // MFMA C/D frag / NT-loadable fp32x4

// byte-offset swizzle for [row][512]-bf16 LDS tiles (row stride 1024B)
#define SWZ(row, kb) (((row) << 10) + ((kb) ^ (((row) & 7) << 4)))

__device__ __forceinline__ ushort f2bu(float f) {
    bf16 h = __float2bfloat16(f); ushort u; __builtin_memcpy(&u, &h, 2); return u;
}
__device__ __forceinline__ float bu2f(ushort u) {
    unsigned x = ((unsigned)u) << 16; float f; __builtin_memcpy(&f, &x, 4); return f;
}

__device__ __forceinline__ float wave_sum(float v) {
#pragma unroll
    for (int off = 32; off >= 1; off >>= 1) v += __shfl_xor(v, off, 64);
    return v;
}

// ---------------- shared building blocks ----------------
// Memory policy (validated R10/R16/R17): NT on single-touch A-loads/C-stores; plain B
// loads (weights L2-resident). NT stores only write-amp-safe as FULL-WAVE 1KB bursts.
// R18: manual B-prefetch compiler-sunk + harmful (k-loop is compiler-owned).
// R19: epilogue barriers not binding. R20: restore TLP (16 waves, 4/SIMD) on the
// wide tile — same intensity, double the stall coverage (Occ was 23% = 2 waves/SIMD).

// stage A[BM][512] -> sA (bf16, swizzled, NT 16B loads); 1024 threads
template <int BM, bool SPARSEA, bool AF32>
__device__ __forceinline__ void stage_A(char* sA, const ushort* __restrict__ Ab,
                                        const float* __restrict__ Af, size_t m0, int tid) {
    for (int c = tid; c < BM * 64; c += 1024) {
        const int row = c >> 6, k8 = (c & 63) << 3;
        const size_t L = m0 + row;
        const size_t pr = SPARSEA ? ((L >> 4) * 32 + (L & 15)) : L;
        s8v o;
        if constexpr (AF32) {
            const float* src = Af + pr * D + k8;
            const f4v v0 = __builtin_nontemporal_load((const f4v*)src);
            const f4v v1 = __builtin_nontemporal_load((const f4v*)(src + 4));
            o = s8v{(short)f2bu(v0.x), (short)f2bu(v0.y), (short)f2bu(v0.z), (short)f2bu(v0.w),
                    (short)f2bu(v1.x), (short)f2bu(v1.y), (short)f2bu(v1.z), (short)f2bu(v1.w)};
        } else {
            o = __builtin_nontemporal_load((const s8v*)(Ab + pr * D + k8));
        }
        *(s8v*)(sA + SWZ(row, k8 * 2)) = o;
    }
}

// LayerNorm rows of sA in place (one wave per row, 16 waves)
template <int BM>
__device__ __forceinline__ void ln_sA(char* sA, const float* __restrict__ lng,
                                      const float* __restrict__ lnb, int lane, int wv) {
    for (int i = wv; i < BM; i += 16) {
        float v[8];
#pragma unroll
        for (int j = 0; j < 8; ++j)
            v[j] = bu2f(*(const ushort*)(sA + SWZ(i, 2 * (lane + 64 * j))));
        float s = 0.f;
#pragma unroll
        for (int j = 0; j < 8; ++j) s += v[j];
        s = wave_sum(s);
        const float mu = s * (1.f / 512.f);
        float q2 = 0.f;
#pragma unroll
        for (int j = 0; j < 8; ++j) { const float t = v[j] - mu; q2 = fmaf(t, t, q2); }
        q2 = wave_sum(q2);
        const float inv = rsqrtf(q2 * (1.f / 512.f) + 1e-5f);
#pragma unroll
        for (int j = 0; j < 8; ++j) {
            const int d0 = lane + 64 * j;
            *(ushort*)(sA + SWZ(i, 2 * d0)) = f2bu((v[j] - mu) * inv * lng[d0] + lnb[d0]);
        }
    }
}

// K=512 MFMA loop; wave owns 32 cols (NCT=2). Plain B loads, compiler-scheduled.
template <int RT, int NCT>
__device__ __forceinline__ void run_kloop(const char* sA, const ushort* __restrict__ Wt,
                                          int m, int g, int swm, int wv, f4v (*acc)[NCT]) {
    const ushort* Bp = Wt + ((size_t)(wv * (NCT * 16) + m) << 9) + 8 * g;
#pragma unroll
    for (int k0 = 0; k0 < 512; k0 += 32) {
        s8v bfr[NCT];
#pragma unroll
        for (int ct = 0; ct < NCT; ++ct) bfr[ct] = *(const s8v*)(Bp + ct * 8192 + k0);
        const int kb = 2 * (k0 + 8 * g);
        s8v a[RT];
#pragma unroll
        for (int rt = 0; rt < RT; ++rt)
            a[rt] = *(const s8v*)(sA + ((rt * 16 + m) << 10) + (kb ^ swm));
#pragma unroll
        for (int ct = 0; ct < NCT; ++ct)
#pragma unroll
            for (int rt = 0; rt < RT; ++rt)
                acc[rt][ct] = __builtin_amdgcn_mfma_f32_16x16x32_bf16(a[rt], bfr[ct], acc[rt][ct], 0, 0, 0);
    }
}

// epilogue: paired stripes through 32KB sC -> full-wave 1KB NT bursts (write-amp-safe).
// Rule #20: all loops fully unrolled (runtime acc index -> scratch, R7 blowup).
template <int RT, int NCT, bool RESFUSE>
__device__ __forceinline__ void epilogue_out(const f4v (*acc)[NCT], const float* __restrict__ bb,
                                             const char* sA, char* sC, ushort* __restrict__ Cb,
                                             size_t m0, int tid, int lane, int wv) {
    const int m = lane & 15, g = lane >> 4;
#pragma unroll
    for (int rp = 0; rp < RT; rp += 2) {   // FULLY UNROLLED (rule #20)
        __syncthreads();   // sC free (previous pair copied out / first use)
#pragma unroll
        for (int su = 0; su < 2; ++su) {
            const int rt = rp + su;
#pragma unroll
            for (int ct = 0; ct < NCT; ++ct) {
                const int col = wv * (NCT * 16) + ct * 16 + m;
                const float bv = bb[col];
#pragma unroll
                for (int r = 0; r < 4; ++r) {
                    const int lrow = g * 4 + r;
                    float v = acc[rt][ct][r] + bv;
                    if (RESFUSE)
                        v = bu2f(*(const ushort*)(sA + SWZ(rt * 16 + lrow, 2 * col))) + fmaxf(v, 0.f);
                    *(ushort*)(sC + SWZ(su * 16 + lrow, 2 * col)) = f2bu(v);
                }
            }
        }
        __syncthreads();
        // coalesced copy-out: 32 rows x 1KB, full-wave bursts, NT 16B stores
        for (int c = tid; c < 32 * 64; c += 1024) {
            const int row = c >> 6, k8 = (c & 63) << 3;
            __builtin_nontemporal_store(*(const s8v*)(sC + SWZ(row, k8 * 2)),
                                        (s8v*)(Cb + (m0 + rp * 16 + row) * D + k8));
        }
    }
    __syncthreads();
}

// ---------------- weight pre-transpose + Q0 (unchanged) ----------------
struct WPtrs { const float* s[7]; };

__global__ __launch_bounds__(256) void wtrans7(WPtrs wp, ushort* __restrict__ Wt) {
    const float* W = wp.s[blockIdx.z];
    ushort* dst = Wt + (size_t)blockIdx.z * 262144;
    __shared__ float t[32][33];
    const int k0 = blockIdx.x * 32, n0 = blockIdx.y * 32;
    const int lx = threadIdx.x & 31, ly = threadIdx.x >> 5;
    for (int i = ly; i < 32; i += 8) t[i][lx] = W[(size_t)(k0 + i) * D + n0 + lx];
    __syncthreads();
    for (int i = ly; i < 32; i += 8)
        dst[(size_t)(n0 + i) * D + k0 + lx] = f2bu(t[lx][i]);
}

__global__ __launch_bounds__(256) void q0_kernel(
    const float* __restrict__ I, const float* __restrict__ Wq,
    const float* __restrict__ bq, ushort* __restrict__ Q0b)
{
    const int q = blockIdx.x;
    const int c = threadIdx.x;
    float a0 = 0.f, a1 = 0.f;
    for (int k = 0; k < D; ++k) {
        const float iv = I[q * D + k];
        a0 = fmaf(iv, Wq[(size_t)k * D + c], a0);
        a1 = fmaf(iv, Wq[(size_t)k * D + c + 256], a1);
    }
    Q0b[q * D + c]       = f2bu(a0 + bq[c]);
    Q0b[q * D + c + 256] = f2bu(a1 + bq[c + 256]);
}

// ---------------- multi-output batched GEMM: wide tile + 16 waves (4/SIMD) ----------------
// BM=128: sA 128KB + sC 32KB = 160KB, 1 block/CU, 1024 threads. Same per-block traffic
// and intensity as R19; per-wave work halves (NCT=2) -> 2x waves/SIMD for stall coverage.
template <int BM, int MINW, int NOUT, bool RESFUSE, bool LNA, bool SPARSEA, bool AF32>
__global__ __launch_bounds__(1024, MINW) void gemmT(
    const ushort* __restrict__ Ab, const float* __restrict__ Af,
    const ushort* __restrict__ Wt0, const float* __restrict__ bias0, ushort* __restrict__ C0,
    const ushort* __restrict__ Wt1, const float* __restrict__ bias1, ushort* __restrict__ C1,
    const ushort* __restrict__ Wt2, const float* __restrict__ bias2, ushort* __restrict__ C2,
    const float* __restrict__ lng, const float* __restrict__ lnb)
{
    constexpr int RT = BM / 16;
    constexpr int NCT = 2;   // 16 waves x 32 cols
    __shared__ __align__(16) char sA[BM * 1024];
    __shared__ __align__(16) char sC[32 * 1024];
    const int tid = threadIdx.x, lane = tid & 63, wv = tid >> 6;
    const size_t m0 = (size_t)blockIdx.x * BM;

    stage_A<BM, SPARSEA, AF32>(sA, Ab, Af, m0, tid);
    __syncthreads();
    if constexpr (LNA) { ln_sA<BM>(sA, lng, lnb, lane, wv); __syncthreads(); }

    const int m = lane & 15, g = lane >> 4;
    const int swm = (m & 7) << 4;
    const ushort* Wts[3]  = {Wt0, Wt1, Wt2};
    const float*  bias[3] = {bias0, bias1, bias2};
    ushort*       Cs[3]   = {C0, C1, C2};

#pragma unroll
    for (int o = 0; o < NOUT; ++o) {
        f4v acc[RT][NCT];
#pragma unroll
        for (int i = 0; i < RT; ++i)
#pragma unroll
            for (int j = 0; j < NCT; ++j) acc[i][j] = (f4v){0.f, 0.f, 0.f, 0.f};
        run_kloop<RT, NCT>(sA, Wts[o], m, g, swm, wv, acc);
        epilogue_out<RT, NCT, RESFUSE>(acc, bias[o], sA, sC, Cs[o], m0, tid, lane, wv);
    }
}

// ---------------- per-(batch, head) attention core (unchanged, validated) ----------------
template <int SQ, int SK, bool QSHARED, int OSTR>
__global__ __launch_bounds__(64) void attn_core(
    const ushort* __restrict__ Qb, const ushort* __restrict__ Kb,
    const ushort* __restrict__ Vb, ushort* __restrict__ Ob)
{
    constexpr int RS = 72;
    __shared__ __align__(16) ushort sQ[SQ * RS];
    __shared__ __align__(16) ushort sK[SK * RS];
    __shared__ __align__(16) ushort sV[SK * RS];
    __shared__ float sS[SQ][SK + 1];

    const int lane = threadIdx.x;
    const int b = blockIdx.x, h = blockIdx.y;
    const size_t qbase = (QSHARED ? (size_t)0 : (size_t)b * SQ * D) + h * 64;
    const size_t kbase = (size_t)b * SK * D + h * 64;

    for (int idx = lane; idx < SQ * 16; idx += 64) {
        const int r = idx >> 4, c4 = (idx & 15) << 2;
        *(s4v*)(sQ + r * RS + c4) = *(const s4v*)(Qb + qbase + (size_t)r * D + c4);
    }
    for (int idx = lane; idx < SK * 16; idx += 64) {
        const int r = idx >> 4, c4 = (idx & 15) << 2;
        *(s4v*)(sK + r * RS + c4) = *(const s4v*)(Kb + kbase + (size_t)r * D + c4);
        *(s4v*)(sV + r * RS + c4) = *(const s4v*)(Vb + kbase + (size_t)r * D + c4);
    }
    __syncthreads();

    const float scale = 0.044194173824159216f;
#pragma unroll
    for (int o = 0; o < SQ * SK / 64; ++o) {
        const int idx = o * 64 + lane;
        const int q = idx / SK, k = idx % SK;
        float s = 0.f;
#pragma unroll
        for (int dd = 0; dd < 64; dd += 8) {
            const s8v aq = *(const s8v*)(sQ + q * RS + dd);
            const s8v ak = *(const s8v*)(sK + k * RS + dd);
#pragma unroll
            for (int e = 0; e < 8; ++e)
                s = fmaf(bu2f((ushort)aq[e]), bu2f((ushort)ak[e]), s);
        }
        sS[q][k] = s * scale;
    }
    __syncthreads();

    if (lane < SQ) {
        float* row = sS[lane];
        float mx = row[0];
#pragma unroll
        for (int k = 1; k < SK; ++k) mx = fmaxf(mx, row[k]);
        float sum = 0.f;
#pragma unroll
        for (int k = 0; k < SK; ++k) { const float e = __expf(row[k] - mx); row[k] = e; sum += e; }
        const float inv = 1.f / sum;
#pragma unroll
        for (int k = 0; k < SK; ++k) row[k] *= inv;
    }
    __syncthreads();

    float acc[SQ];
#pragma unroll
    for (int q = 0; q < SQ; ++q) acc[q] = 0.f;
#pragma unroll 4
    for (int k = 0; k < SK; ++k) {
        const float v = bu2f(sV[k * RS + lane]);
#pragma unroll
        for (int q = 0; q < SQ; ++q) acc[q] = fmaf(sS[q][k], v, acc[q]);
    }
    const size_t obase = (size_t)b * OSTR * D + h * 64 + lane;
#pragma unroll
    for (int q = 0; q < SQ; ++q)
        Ob[obase + (size_t)q * D] = f2bu(bu2f(sQ[q * RS + lane]) + acc[q]);
}

// ---------------- final: row-LN + mean pool (unchanged, validated) ----------------
__global__ __launch_bounds__(512) void ln_meanpool(
    const ushort* __restrict__ U, const float* __restrict__ gg,
    const float* __restrict__ bb, float* __restrict__ outp)
{
    __shared__ float sP[8][512];
    const int tid = threadIdx.x, lane = tid & 63, wv = tid >> 6;
    const size_t b = blockIdx.x;
    float a[8];
#pragma unroll
    for (int j = 0; j < 8; ++j) a[j] = 0.f;
    for (int i = wv; i < 32; i += 8) {
        const ushort* u = U + ((size_t)b * 32 + i) * D;
        float v[8];
#pragma unroll
        for (int j = 0; j < 8; ++j) v[j] = bu2f(u[lane + 64 * j]);
        float s = 0.f;
#pragma unroll
        for (int j = 0; j < 8; ++j) s += v[j];
        s = wave_sum(s);
        const float mu = s * (1.f / 512.f);
        float q2 = 0.f;
#pragma unroll
        for (int j = 0; j < 8; ++j) { const float t = v[j] - mu; q2 = fmaf(t, t, q2); }
        q2 = wave_sum(q2);
        const float inv = rsqrtf(q2 * (1.f / 512.f) + 1e-5f);
#pragma unroll
        for (int j = 0; j < 8; ++j) {
            const int d0 = lane + 64 * j;
            a[j] += (v[j] - mu) * inv * gg[d0] + bb[d0];
        }
    }
#pragma unroll
    for (int j = 0; j < 8; ++j) sP[wv][lane + 64 * j] = a[j];
    __syncthreads();
    float s = 0.f;
#pragma unroll
    for (int w = 0; w < 8; ++w) s += sP[w][tid];
    outp[b * D + tid] = s * (1.f / 32.f);
}

extern "C" void kernel_launch(void* const* d_in, const int* in_sizes, int n_in,
                              void* d_out, int out_size, void* d_ws, size_t ws_size,
                              hipStream_t stream) {
    (void)in_sizes; (void)n_in; (void)out_size; (void)ws_size;

    const float* x     = (const float*)d_in[0];
    const float* I     = (const float*)d_in[1];
    const float* W0    = (const float*)d_in[2];
    const float* bqkv0 = (const float*)d_in[3];
    const float* Wo0   = (const float*)d_in[4];
    const float* bo0   = (const float*)d_in[5];
    const float* g00   = (const float*)d_in[6];
    const float* b00   = (const float*)d_in[7];
    const float* g01   = (const float*)d_in[8];
    const float* b01   = (const float*)d_in[9];
    const float* W1    = (const float*)d_in[10];
    const float* bqkv1 = (const float*)d_in[11];
    const float* Wo1   = (const float*)d_in[12];
    const float* bo1   = (const float*)d_in[13];
    const float* g10   = (const float*)d_in[14];
    const float* b10   = (const float*)d_in[15];
    const float* g11   = (const float*)d_in[16];
    const float* b11   = (const float*)d_in[17];

    const float* Wq0 = W0;     const float* Wk0 = W0 + D * D;  const float* Wv0 = W0 + 2 * D * D;
    const float* bq0 = bqkv0;  const float* bk0 = bqkv0 + D;   const float* bv0 = bqkv0 + 2 * D;
    const float* Wq1 = W1;     const float* Wk1 = W1 + D * D;  const float* Wv1 = W1 + 2 * D * D;
    const float* bq1 = bqkv1;  const float* bk1 = bqkv1 + D;   const float* bv1 = bqkv1 + 2 * D;

    // ---- workspace: Q0b | Wt(7x512KB) | P0..P3 (64MB each) ----
    char* ws = (char*)d_ws;
    ushort* Q0b = (ushort*)ws;
    ushort* Wt  = (ushort*)(ws + 32768);
    char* base = ws + 32768 + 7 * 524288;
    ushort* P0 = (ushort*)(base);
    ushort* P1 = (ushort*)(base + ((size_t)64 << 20));
    ushort* P2 = (ushort*)(base + ((size_t)128 << 20));
    ushort* P3 = (ushort*)(base + ((size_t)192 << 20));
    const size_t HALFE = (size_t)16 << 20;   // 32MB in ushorts
    ushort* P1hi = P1 + HALFE;

    ushort* WtK0 = Wt + 0 * 262144;
    ushort* WtV0 = Wt + 1 * 262144;
    ushort* WtO0 = Wt + 2 * 262144;
    ushort* WtQ1 = Wt + 3 * 262144;
    ushort* WtK1 = Wt + 4 * 262144;
    ushort* WtV1 = Wt + 5 * 262144;
    ushort* WtO1 = Wt + 6 * 262144;

    WPtrs wp; wp.s[0] = Wk0; wp.s[1] = Wv0; wp.s[2] = Wo0; wp.s[3] = Wq1;
    wp.s[4] = Wk1; wp.s[5] = Wv1; wp.s[6] = Wo1;
    wtrans7<<<dim3(16, 16, 7), 256, 0, stream>>>(wp, Wt);
    q0_kernel<<<MIND, 256, 0, stream>>>(I, Wq0, bq0, Q0b);

    constexpr int GW  = BATCH * SEQ / 128;   // 512 blocks (M = 65536, BM=128)
    constexpr int GWM = BATCH * MIND / 128;  // 256 blocks (M = 32768, BM=128)
    const dim3 ag(BATCH, 8);

    for (int isab = 0; isab < 2; ++isab) {
        // wide triple: {K0,V0,Q1} = proj(A); isab0: A = x (fp32, conv fused); isab1: A = ln(U1)
        if (isab == 0)
            gemmT<128, 4, 3, false, false, false, true><<<GW, 1024, 0, stream>>>(
                nullptr, x, WtK0, bk0, P1, WtV0, bv0, P2, WtQ1, bq1, P3, nullptr, nullptr);
        else
            gemmT<128, 4, 3, false, true, false, false><<<GW, 1024, 0, stream>>>(
                P0, nullptr, WtK0, bk0, P1, WtV0, bv0, P2, WtQ1, bq1, P3, g11, b11);
        // mab0 attention: O0 interleaved into P1 (rows b*32+q, q<16)
        attn_core<MIND, SEQ, true, 32><<<ag, 64, 0, stream>>>(Q0b, P1, P2, P1);
        // U0 = ln0(O0) + relu(ln0(O0)@Wo0+bo0)  (sparse A rows) -> P2.lo
        gemmT<128, 4, 1, true, true, true, false><<<GWM, 1024, 0, stream>>>(
            P1, nullptr, WtO0, bo0, P2, nullptr, nullptr, nullptr, nullptr, nullptr, nullptr, g00, b00);
        // dual: {K1,V1} = proj(ln1(U0))  -> P1.lo / P1.hi
        gemmT<128, 4, 2, false, true, false, false><<<GWM, 1024, 0, stream>>>(
            P2, nullptr, WtK1, bk1, P1, WtV1, bv1, P1hi, nullptr, nullptr, nullptr, g01, b01);
        // mab1 attention: Q=P3, K/V=P1 halves; O1 in-place into P3
        attn_core<SEQ, MIND, false, 32><<<ag, 64, 0, stream>>>(P3, P1, P1hi, P3);
        // U1 = ln0(O1) + relu(ln0(O1)@Wo1+bo1) -> P0
        gemmT<128, 4, 1, true, true, false, false><<<GW, 1024, 0, stream>>>(
            P3, nullptr, WtO1, bo1, P0, nullptr, nullptr, nullptr, nullptr, nullptr, nullptr, g10, b10);
    }

    ln_meanpool<<<BATCH, 512, 0, stream>>>(P0, g11, b11, (float*)d_out);
}

// Round 21
// 1253.448 us; speedup vs baseline: 1.0202x; 1.0202x over previous
//
#include <hip/hip_runtime.h>
#include <hip/hip_bf16.h>

#define D 512
#define BATCH 2048
#define SEQ 32
#define MIND 16

typedef __hip_bfloat16 bf16;
typedef __attribute__((ext_vector_type(8))) short s8v;   // 8 bf16 = 16B (MFMA A/B frag)
typedef __attribute__((ext_vector_type(4))) short s4v;
typedef __attribute__((ext_vector_type(4))) float f4v;   // MFMA C/D frag / NT-loadable fp32x4

// byte-offset swizzle for [row][512]-bf16 LDS tiles (row stride 1024B)
#define SWZ(row, kb) (((row) << 10) + ((kb) ^ (((row) & 7) << 4)))

__device__ __forceinline__ ushort f2bu(float f) {
    bf16 h = __float2bfloat16(f); ushort u; __builtin_memcpy(&u, &h, 2); return u;
}
__device__ __forceinline__ float bu2f(ushort u) {
    unsigned x = ((unsigned)u) << 16; float f; __builtin_memcpy(&f, &x, 4); return f;
}

__device__ __forceinline__ float wave_sum(float v) {
#pragma unroll
    for (int off = 32; off >= 1; off >>= 1) v += __shfl_xor(v, off, 64);
    return v;
}

// ---------------- shared building blocks (final, R19 = best verified 1257us) ----------------
// Ledger: NT on single-touch A/C streams + plain B loads (R10/R15); full-wave 1KB NT
// bursts only write-amp-safe shape (R13/R14); BM=128 intensity (R16/R17); 8 waves
// optimal vs 16 (R20: FETCH+62%); manual prefetch compiler-sunk (R11/R18); epilogue
// barriers not binding (R19); chain fusion worse (R12). Latency plateau at source level.

template <int BM, bool SPARSEA, bool AF32>
__device__ __forceinline__ void stage_A(char* sA, const ushort* __restrict__ Ab,
                                        const float* __restrict__ Af, size_t m0, int tid) {
    for (int c = tid; c < BM * 64; c += 512) {
        const int row = c >> 6, k8 = (c & 63) << 3;
        const size_t L = m0 + row;
        const size_t pr = SPARSEA ? ((L >> 4) * 32 + (L & 15)) : L;
        s8v o;
        if constexpr (AF32) {
            const float* src = Af + pr * D + k8;
            const f4v v0 = __builtin_nontemporal_load((const f4v*)src);
            const f4v v1 = __builtin_nontemporal_load((const f4v*)(src + 4));
            o = s8v{(short)f2bu(v0.x), (short)f2bu(v0.y), (short)f2bu(v0.z), (short)f2bu(v0.w),
                    (short)f2bu(v1.x), (short)f2bu(v1.y), (short)f2bu(v1.z), (short)f2bu(v1.w)};
        } else {
            o = __builtin_nontemporal_load((const s8v*)(Ab + pr * D + k8));
        }
        *(s8v*)(sA + SWZ(row, k8 * 2)) = o;
    }
}

template <int BM>
__device__ __forceinline__ void ln_sA(char* sA, const float* __restrict__ lng,
                                      const float* __restrict__ lnb, int lane, int wv) {
    for (int i = wv; i < BM; i += 8) {
        float v[8];
#pragma unroll
        for (int j = 0; j < 8; ++j)
            v[j] = bu2f(*(const ushort*)(sA + SWZ(i, 2 * (lane + 64 * j))));
        float s = 0.f;
#pragma unroll
        for (int j = 0; j < 8; ++j) s += v[j];
        s = wave_sum(s);
        const float mu = s * (1.f / 512.f);
        float q2 = 0.f;
#pragma unroll
        for (int j = 0; j < 8; ++j) { const float t = v[j] - mu; q2 = fmaf(t, t, q2); }
        q2 = wave_sum(q2);
        const float inv = rsqrtf(q2 * (1.f / 512.f) + 1e-5f);
#pragma unroll
        for (int j = 0; j < 8; ++j) {
            const int d0 = lane + 64 * j;
            *(ushort*)(sA + SWZ(i, 2 * d0)) = f2bu((v[j] - mu) * inv * lng[d0] + lnb[d0]);
        }
    }
}

// K=512 MFMA loop (plain B loads; compiler-scheduled — manual prefetch is sunk, R18)
template <int RT>
__device__ __forceinline__ void run_kloop(const char* sA, const ushort* __restrict__ Wt,
                                          int m, int g, int swm, int wv, f4v (*acc)[4]) {
    const ushort* Bp = Wt + ((size_t)(wv * 64 + m) << 9) + 8 * g;
#pragma unroll
    for (int k0 = 0; k0 < 512; k0 += 32) {
        s8v bfr[4];
#pragma unroll
        for (int ct = 0; ct < 4; ++ct) bfr[ct] = *(const s8v*)(Bp + ct * 8192 + k0);
        const int kb = 2 * (k0 + 8 * g);
        s8v a[RT];
#pragma unroll
        for (int rt = 0; rt < RT; ++rt)
            a[rt] = *(const s8v*)(sA + ((rt * 16 + m) << 10) + (kb ^ swm));
#pragma unroll
        for (int ct = 0; ct < 4; ++ct)
#pragma unroll
            for (int rt = 0; rt < RT; ++rt)
                acc[rt][ct] = __builtin_amdgcn_mfma_f32_16x16x32_bf16(a[rt], bfr[ct], acc[rt][ct], 0, 0, 0);
    }
}

// epilogue: PAIRED stripes through 32KB sC; copy-out = full-wave 1KB NT bursts.
// Rule #20: all loops fully unrolled (runtime acc index -> scratch, R7 blowup).
template <int RT, bool RESFUSE>
__device__ __forceinline__ void epilogue_out(const f4v (*acc)[4], const float* __restrict__ bb,
                                             const char* sA, char* sC, ushort* __restrict__ Cb,
                                             size_t m0, int tid, int lane, int wv) {
    const int m = lane & 15, g = lane >> 4;
#pragma unroll
    for (int rp = 0; rp < RT; rp += 2) {   // FULLY UNROLLED (rule #20)
        __syncthreads();   // sC free (previous pair copied out / first use)
#pragma unroll
        for (int su = 0; su < 2; ++su) {
            const int rt = rp + su;
#pragma unroll
            for (int ct = 0; ct < 4; ++ct) {
                const int col = wv * 64 + ct * 16 + m;
                const float bv = bb[col];
#pragma unroll
                for (int r = 0; r < 4; ++r) {
                    const int lrow = g * 4 + r;
                    float v = acc[rt][ct][r] + bv;
                    if (RESFUSE)
                        v = bu2f(*(const ushort*)(sA + SWZ(rt * 16 + lrow, 2 * col))) + fmaxf(v, 0.f);
                    *(ushort*)(sC + SWZ(su * 16 + lrow, 2 * col)) = f2bu(v);
                }
            }
        }
        __syncthreads();
        // coalesced copy-out: 32 rows x 1KB, full-wave bursts, NT 16B stores
        for (int c = tid; c < 32 * 64; c += 512) {
            const int row = c >> 6, k8 = (c & 63) << 3;
            __builtin_nontemporal_store(*(const s8v*)(sC + SWZ(row, k8 * 2)),
                                        (s8v*)(Cb + (m0 + rp * 16 + row) * D + k8));
        }
    }
    __syncthreads();
}

// ---------------- weight pre-transpose + Q0 ----------------
struct WPtrs { const float* s[7]; };

__global__ __launch_bounds__(256) void wtrans7(WPtrs wp, ushort* __restrict__ Wt) {
    const float* W = wp.s[blockIdx.z];
    ushort* dst = Wt + (size_t)blockIdx.z * 262144;
    __shared__ float t[32][33];
    const int k0 = blockIdx.x * 32, n0 = blockIdx.y * 32;
    const int lx = threadIdx.x & 31, ly = threadIdx.x >> 5;
    for (int i = ly; i < 32; i += 8) t[i][lx] = W[(size_t)(k0 + i) * D + n0 + lx];
    __syncthreads();
    for (int i = ly; i < 32; i += 8)
        dst[(size_t)(n0 + i) * D + k0 + lx] = f2bu(t[lx][i]);
}

__global__ __launch_bounds__(256) void q0_kernel(
    const float* __restrict__ I, const float* __restrict__ Wq,
    const float* __restrict__ bq, ushort* __restrict__ Q0b)
{
    const int q = blockIdx.x;
    const int c = threadIdx.x;
    float a0 = 0.f, a1 = 0.f;
    for (int k = 0; k < D; ++k) {
        const float iv = I[q * D + k];
        a0 = fmaf(iv, Wq[(size_t)k * D + c], a0);
        a1 = fmaf(iv, Wq[(size_t)k * D + c + 256], a1);
    }
    Q0b[q * D + c]       = f2bu(a0 + bq[c]);
    Q0b[q * D + c + 256] = f2bu(a1 + bq[c + 256]);
}

// ---------------- multi-output batched GEMM (BM=128, 8 waves, paired-stripe epilogue) ----------------
// sA 128KB + sC 32KB = 160KB (per-CU max), 1 block/CU, (512,2).
template <int BM, int MINW, int NOUT, bool RESFUSE, bool LNA, bool SPARSEA, bool AF32>
__global__ __launch_bounds__(512, MINW) void gemmT(
    const ushort* __restrict__ Ab, const float* __restrict__ Af,
    const ushort* __restrict__ Wt0, const float* __restrict__ bias0, ushort* __restrict__ C0,
    const ushort* __restrict__ Wt1, const float* __restrict__ bias1, ushort* __restrict__ C1,
    const ushort* __restrict__ Wt2, const float* __restrict__ bias2, ushort* __restrict__ C2,
    const float* __restrict__ lng, const float* __restrict__ lnb)
{
    constexpr int RT = BM / 16;
    __shared__ __align__(16) char sA[BM * 1024];
    __shared__ __align__(16) char sC[32 * 1024];
    const int tid = threadIdx.x, lane = tid & 63, wv = tid >> 6;
    const size_t m0 = (size_t)blockIdx.x * BM;

    stage_A<BM, SPARSEA, AF32>(sA, Ab, Af, m0, tid);
    __syncthreads();
    if constexpr (LNA) { ln_sA<BM>(sA, lng, lnb, lane, wv); __syncthreads(); }

    const int m = lane & 15, g = lane >> 4;
    const int swm = (m & 7) << 4;
    const ushort* Wts[3]  = {Wt0, Wt1, Wt2};
    const float*  bias[3] = {bias0, bias1, bias2};
    ushort*       Cs[3]   = {C0, C1, C2};

#pragma unroll
    for (int o = 0; o < NOUT; ++o) {
        f4v acc[RT][4];
#pragma unroll
        for (int i = 0; i < RT; ++i)
#pragma unroll
            for (int j = 0; j < 4; ++j) acc[i][j] = (f4v){0.f, 0.f, 0.f, 0.f};
        run_kloop<RT>(sA, Wts[o], m, g, swm, wv, acc);
        epilogue_out<RT, RESFUSE>(acc, bias[o], sA, sC, Cs[o], m0, tid, lane, wv);
    }
}

// ---------------- per-(batch, head) attention core ----------------
template <int SQ, int SK, bool QSHARED, int OSTR>
__global__ __launch_bounds__(64) void attn_core(
    const ushort* __restrict__ Qb, const ushort* __restrict__ Kb,
    const ushort* __restrict__ Vb, ushort* __restrict__ Ob)
{
    constexpr int RS = 72;
    __shared__ __align__(16) ushort sQ[SQ * RS];
    __shared__ __align__(16) ushort sK[SK * RS];
    __shared__ __align__(16) ushort sV[SK * RS];
    __shared__ float sS[SQ][SK + 1];

    const int lane = threadIdx.x;
    const int b = blockIdx.x, h = blockIdx.y;
    const size_t qbase = (QSHARED ? (size_t)0 : (size_t)b * SQ * D) + h * 64;
    const size_t kbase = (size_t)b * SK * D + h * 64;

    for (int idx = lane; idx < SQ * 16; idx += 64) {
        const int r = idx >> 4, c4 = (idx & 15) << 2;
        *(s4v*)(sQ + r * RS + c4) = *(const s4v*)(Qb + qbase + (size_t)r * D + c4);
    }
    for (int idx = lane; idx < SK * 16; idx += 64) {
        const int r = idx >> 4, c4 = (idx & 15) << 2;
        *(s4v*)(sK + r * RS + c4) = *(const s4v*)(Kb + kbase + (size_t)r * D + c4);
        *(s4v*)(sV + r * RS + c4) = *(const s4v*)(Vb + kbase + (size_t)r * D + c4);
    }
    __syncthreads();

    const float scale = 0.044194173824159216f;   // 1/sqrt(512)
#pragma unroll
    for (int o = 0; o < SQ * SK / 64; ++o) {
        const int idx = o * 64 + lane;
        const int q = idx / SK, k = idx % SK;
        float s = 0.f;
#pragma unroll
        for (int dd = 0; dd < 64; dd += 8) {
            const s8v aq = *(const s8v*)(sQ + q * RS + dd);
            const s8v ak = *(const s8v*)(sK + k * RS + dd);
#pragma unroll
            for (int e = 0; e < 8; ++e)
                s = fmaf(bu2f((ushort)aq[e]), bu2f((ushort)ak[e]), s);
        }
        sS[q][k] = s * scale;
    }
    __syncthreads();

    if (lane < SQ) {   // softmax over k (serial; SK <= 32)
        float* row = sS[lane];
        float mx = row[0];
#pragma unroll
        for (int k = 1; k < SK; ++k) mx = fmaxf(mx, row[k]);
        float sum = 0.f;
#pragma unroll
        for (int k = 0; k < SK; ++k) { const float e = __expf(row[k] - mx); row[k] = e; sum += e; }
        const float inv = 1.f / sum;
#pragma unroll
        for (int k = 0; k < SK; ++k) row[k] *= inv;
    }
    __syncthreads();

    float acc[SQ];
#pragma unroll
    for (int q = 0; q < SQ; ++q) acc[q] = 0.f;
#pragma unroll 4
    for (int k = 0; k < SK; ++k) {
        const float v = bu2f(sV[k * RS + lane]);
#pragma unroll
        for (int q = 0; q < SQ; ++q) acc[q] = fmaf(sS[q][k], v, acc[q]);
    }
    const size_t obase = (size_t)b * OSTR * D + h * 64 + lane;
#pragma unroll
    for (int q = 0; q < SQ; ++q)
        Ob[obase + (size_t)q * D] = f2bu(bu2f(sQ[q * RS + lane]) + acc[q]);
}

// ---------------- final: row-LN + mean pool ----------------
__global__ __launch_bounds__(512) void ln_meanpool(
    const ushort* __restrict__ U, const float* __restrict__ gg,
    const float* __restrict__ bb, float* __restrict__ outp)
{
    __shared__ float sP[8][512];
    const int tid = threadIdx.x, lane = tid & 63, wv = tid >> 6;
    const size_t b = blockIdx.x;
    float a[8];
#pragma unroll
    for (int j = 0; j < 8; ++j) a[j] = 0.f;
    for (int i = wv; i < 32; i += 8) {
        const ushort* u = U + ((size_t)b * 32 + i) * D;
        float v[8];
#pragma unroll
        for (int j = 0; j < 8; ++j) v[j] = bu2f(u[lane + 64 * j]);
        float s = 0.f;
#pragma unroll
        for (int j = 0; j < 8; ++j) s += v[j];
        s = wave_sum(s);
        const float mu = s * (1.f / 512.f);
        float q2 = 0.f;
#pragma unroll
        for (int j = 0; j < 8; ++j) { const float t = v[j] - mu; q2 = fmaf(t, t, q2); }
        q2 = wave_sum(q2);
        const float inv = rsqrtf(q2 * (1.f / 512.f) + 1e-5f);
#pragma unroll
        for (int j = 0; j < 8; ++j) {
            const int d0 = lane + 64 * j;
            a[j] += (v[j] - mu) * inv * gg[d0] + bb[d0];
        }
    }
#pragma unroll
    for (int j = 0; j < 8; ++j) sP[wv][lane + 64 * j] = a[j];
    __syncthreads();
    float s = 0.f;
#pragma unroll
    for (int w = 0; w < 8; ++w) s += sP[w][tid];
    outp[b * D + tid] = s * (1.f / 32.f);
}

extern "C" void kernel_launch(void* const* d_in, const int* in_sizes, int n_in,
                              void* d_out, int out_size, void* d_ws, size_t ws_size,
                              hipStream_t stream) {
    (void)in_sizes; (void)n_in; (void)out_size; (void)ws_size;

    const float* x     = (const float*)d_in[0];
    const float* I     = (const float*)d_in[1];
    const float* W0    = (const float*)d_in[2];
    const float* bqkv0 = (const float*)d_in[3];
    const float* Wo0   = (const float*)d_in[4];
    const float* bo0   = (const float*)d_in[5];
    const float* g00   = (const float*)d_in[6];
    const float* b00   = (const float*)d_in[7];
    const float* g01   = (const float*)d_in[8];
    const float* b01   = (const float*)d_in[9];
    const float* W1    = (const float*)d_in[10];
    const float* bqkv1 = (const float*)d_in[11];
    const float* Wo1   = (const float*)d_in[12];
    const float* bo1   = (const float*)d_in[13];
    const float* g10   = (const float*)d_in[14];
    const float* b10   = (const float*)d_in[15];
    const float* g11   = (const float*)d_in[16];
    const float* b11   = (const float*)d_in[17];

    const float* Wq0 = W0;     const float* Wk0 = W0 + D * D;  const float* Wv0 = W0 + 2 * D * D;
    const float* bq0 = bqkv0;  const float* bk0 = bqkv0 + D;   const float* bv0 = bqkv0 + 2 * D;
    const float* Wq1 = W1;     const float* Wk1 = W1 + D * D;  const float* Wv1 = W1 + 2 * D * D;
    const float* bq1 = bqkv1;  const float* bk1 = bqkv1 + D;   const float* bv1 = bqkv1 + 2 * D;

    // ---- workspace: Q0b | Wt(7x512KB) | P0..P3 (64MB each) ----
    char* ws = (char*)d_ws;
    ushort* Q0b = (ushort*)ws;
    ushort* Wt  = (ushort*)(ws + 32768);
    char* base = ws + 32768 + 7 * 524288;
    ushort* P0 = (ushort*)(base);
    ushort* P1 = (ushort*)(base + ((size_t)64 << 20));
    ushort* P2 = (ushort*)(base + ((size_t)128 << 20));
    ushort* P3 = (ushort*)(base + ((size_t)192 << 20));
    const size_t HALFE = (size_t)16 << 20;   // 32MB in ushorts
    ushort* P1hi = P1 + HALFE;

    ushort* WtK0 = Wt + 0 * 262144;
    ushort* WtV0 = Wt + 1 * 262144;
    ushort* WtO0 = Wt + 2 * 262144;
    ushort* WtQ1 = Wt + 3 * 262144;
    ushort* WtK1 = Wt + 4 * 262144;
    ushort* WtV1 = Wt + 5 * 262144;
    ushort* WtO1 = Wt + 6 * 262144;

    WPtrs wp; wp.s[0] = Wk0; wp.s[1] = Wv0; wp.s[2] = Wo0; wp.s[3] = Wq1;
    wp.s[4] = Wk1; wp.s[5] = Wv1; wp.s[6] = Wo1;
    wtrans7<<<dim3(16, 16, 7), 256, 0, stream>>>(wp, Wt);
    q0_kernel<<<MIND, 256, 0, stream>>>(I, Wq0, bq0, Q0b);

    constexpr int GW  = BATCH * SEQ / 128;   // 512 blocks (M = 65536, BM=128)
    constexpr int GWM = BATCH * MIND / 128;  // 256 blocks (M = 32768, BM=128)
    const dim3 ag(BATCH, 8);

    for (int isab = 0; isab < 2; ++isab) {
        // wide triple: {K0,V0,Q1} = proj(A); isab0: A = x (fp32, conv fused); isab1: A = ln(U1)
        if (isab == 0)
            gemmT<128, 2, 3, false, false, false, true><<<GW, 512, 0, stream>>>(
                nullptr, x, WtK0, bk0, P1, WtV0, bv0, P2, WtQ1, bq1, P3, nullptr, nullptr);
        else
            gemmT<128, 2, 3, false, true, false, false><<<GW, 512, 0, stream>>>(
                P0, nullptr, WtK0, bk0, P1, WtV0, bv0, P2, WtQ1, bq1, P3, g11, b11);
        // mab0 attention: O0 interleaved into P1 (rows b*32+q, q<16)
        attn_core<MIND, SEQ, true, 32><<<ag, 64, 0, stream>>>(Q0b, P1, P2, P1);
        // U0 = ln0(O0) + relu(ln0(O0)@Wo0+bo0)  (sparse A rows) -> P2.lo
        gemmT<128, 2, 1, true, true, true, false><<<GWM, 512, 0, stream>>>(
            P1, nullptr, WtO0, bo0, P2, nullptr, nullptr, nullptr, nullptr, nullptr, nullptr, g00, b00);
        // dual: {K1,V1} = proj(ln1(U0))  -> P1.lo / P1.hi
        gemmT<128, 2, 2, false, true, false, false><<<GWM, 512, 0, stream>>>(
            P2, nullptr, WtK1, bk1, P1, WtV1, bv1, P1hi, nullptr, nullptr, nullptr, g01, b01);
        // mab1 attention: Q=P3, K/V=P1 halves; O1 in-place into P3
        attn_core<SEQ, MIND, false, 32><<<ag, 64, 0, stream>>>(P3, P1, P1hi, P3);
        // U1 = ln0(O1) + relu(ln0(O1)@Wo1+bo1) -> P0
        gemmT<128, 2, 1, true, true, false, false><<<GW, 512, 0, stream>>>(
            P3, nullptr, WtO1, bo1, P0, nullptr, nullptr, nullptr, nullptr, nullptr, nullptr, g10, b10);
    }

    ln_meanpool<<<BATCH, 512, 0, stream>>>(P0, g11, b11, (float*)d_out);
}